// Round 1
// baseline (1560.708 us; speedup 1.0000x reference)
//
#include <hip/hip_runtime.h>
#include <math.h>

// Problem constants (B=1, L=4096, HIDDEN=1024, 16 heads x 64)
constexpr int DM = 1024;
constexpr int NH = 16;
constexpr int HD = 64;

// ---------------------------------------------------------------------------
// GEMM: C[M][N] = A[M][K] * B[N][K]^T   (torch Linear: dot of rows)
// BM=128, BN=64, BK=16; 256 threads; 8x4 accumulator per thread.
// LDS stored transposed [BK][tile] so the inner loop is an outer product with
// conflict-free b128 reads (a-side broadcast, b-side 2-way = free).
// ---------------------------------------------------------------------------
__global__ __launch_bounds__(256, 2)
void gemm_abt(const float* __restrict__ A, const float* __restrict__ B,
              float* __restrict__ C, int M, int N, int K) {
    constexpr int BM = 128, BN = 64, BK = 16;
    constexpr int PA = 132;  // pad for As rows
    constexpr int PB = 68;   // pad for Bs rows
    __shared__ float As[BK][PA];
    __shared__ float Bs[BK][PB];

    const int bm = blockIdx.y * BM;
    const int bn = blockIdx.x * BN;
    const int t  = threadIdx.x;
    const int tx = t & 15;        // 0..15 -> 4 cols
    const int ty = t >> 4;        // 0..15 -> 4+4 rows (split by 64)

    const int lrA = t >> 1;            // 0..127
    const int lcA = (t & 1) * 8;       // 0 or 8
    const int lrB = t >> 2;            // 0..63
    const int lcB = (t & 3) * 4;       // 0,4,8,12

    float acc0[4][4] = {};
    float acc1[4][4] = {};

    const float* Arow = A + (size_t)(bm + lrA) * K + lcA;
    const float* Brow = B + (size_t)(bn + lrB) * K + lcB;

    for (int k0 = 0; k0 < K; k0 += BK) {
        float4 av0 = *reinterpret_cast<const float4*>(Arow + k0);
        float4 av1 = *reinterpret_cast<const float4*>(Arow + k0 + 4);
        float4 bv  = *reinterpret_cast<const float4*>(Brow + k0);
        __syncthreads();
        As[lcA + 0][lrA] = av0.x; As[lcA + 1][lrA] = av0.y;
        As[lcA + 2][lrA] = av0.z; As[lcA + 3][lrA] = av0.w;
        As[lcA + 4][lrA] = av1.x; As[lcA + 5][lrA] = av1.y;
        As[lcA + 6][lrA] = av1.z; As[lcA + 7][lrA] = av1.w;
        Bs[lcB + 0][lrB] = bv.x;  Bs[lcB + 1][lrB] = bv.y;
        Bs[lcB + 2][lrB] = bv.z;  Bs[lcB + 3][lrB] = bv.w;
        __syncthreads();
#pragma unroll
        for (int kk = 0; kk < BK; ++kk) {
            float a0[4], a1[4], b0[4];
            *reinterpret_cast<float4*>(a0) = *reinterpret_cast<const float4*>(&As[kk][ty * 4]);
            *reinterpret_cast<float4*>(a1) = *reinterpret_cast<const float4*>(&As[kk][64 + ty * 4]);
            *reinterpret_cast<float4*>(b0) = *reinterpret_cast<const float4*>(&Bs[kk][tx * 4]);
#pragma unroll
            for (int i = 0; i < 4; ++i)
#pragma unroll
                for (int j = 0; j < 4; ++j) {
                    acc0[i][j] += a0[i] * b0[j];
                    acc1[i][j] += a1[i] * b0[j];
                }
        }
    }
#pragma unroll
    for (int i = 0; i < 4; ++i) {
        float4 o0 = make_float4(acc0[i][0], acc0[i][1], acc0[i][2], acc0[i][3]);
        float4 o1 = make_float4(acc1[i][0], acc1[i][1], acc1[i][2], acc1[i][3]);
        *reinterpret_cast<float4*>(&C[(size_t)(bm + ty * 4 + i) * N + bn + tx * 4])      = o0;
        *reinterpret_cast<float4*>(&C[(size_t)(bm + 64 + ty * 4 + i) * N + bn + tx * 4]) = o1;
    }
}

// ---------------------------------------------------------------------------
// In-place RoPE on q and k: out[j]    = a*cos - b*sin   (j <  32)
//                           out[j+32] = b*cos + a*sin
// cos/sin computed on device (only 2 transcendental pairs per element pair).
// ---------------------------------------------------------------------------
__global__ __launch_bounds__(512)
void rope_kernel(float* __restrict__ q, float* __restrict__ k) {
    const int l = blockIdx.x;
    const int j = threadIdx.x & 31;
    const int h = threadIdx.x >> 5;
    // inv_freq = 10000^(-j/32) = 2^(-j/32 * log2(10000))
    const float inv = exp2f(-(float)j * (13.287712379549449f / 32.0f));
    const float ang = (float)l * inv;
    float s, c;
    sincosf(ang, &s, &c);
    const size_t base = (size_t)l * DM + h * HD + j;
    float a = q[base], b = q[base + 32];
    q[base]      = a * c - b * s;
    q[base + 32] = b * c + a * s;
    a = k[base]; b = k[base + 32];
    k[base]      = a * c - b * s;
    k[base + 32] = b * c + a * s;
}

// ---------------------------------------------------------------------------
// fp32 causal flash attention. One block per (q-tile of 64 rows, head).
// Q,K stored transposed in LDS ([d][row]) so S = QK^T is an outer product
// over d with conflict-free reads; P stored transposed for the PV product.
// ---------------------------------------------------------------------------
__global__ __launch_bounds__(256, 2)
void flash_attn(const float* __restrict__ q, const float* __restrict__ k,
                const float* __restrict__ v, float* __restrict__ out, int L) {
    constexpr int BQ = 64, BKV = 64, PQ = 68;
    __shared__ float Qst[HD][PQ];   // [d][row], pre-scaled by 1/8
    __shared__ float Kst[HD][PQ];   // [d][row]
    __shared__ float Vs[BKV][HD];   // natural
    __shared__ float Pst[BKV][PQ];  // [col][row]

    const int h  = blockIdx.y;
    const int qt = blockIdx.x;
    const int q0 = qt * BQ;
    const int t  = threadIdx.x;
    const int tx = t & 15;
    const int ty = t >> 4;

    // Load Q tile transposed, scaled by 1/sqrt(64)
    {
        const int d0 = (t & 15) * 4;
        const int rb = t >> 4;  // 0..15
#pragma unroll
        for (int rr = 0; rr < 4; ++rr) {
            const int r = rb + rr * 16;
            float4 qv = *reinterpret_cast<const float4*>(&q[(size_t)(q0 + r) * DM + h * HD + d0]);
            Qst[d0 + 0][r] = qv.x * 0.125f;
            Qst[d0 + 1][r] = qv.y * 0.125f;
            Qst[d0 + 2][r] = qv.z * 0.125f;
            Qst[d0 + 3][r] = qv.w * 0.125f;
        }
    }

    float m_i[4], l_i[4], oa[4][4];
#pragma unroll
    for (int i = 0; i < 4; ++i) {
        m_i[i] = -INFINITY; l_i[i] = 0.f;
#pragma unroll
        for (int j = 0; j < 4; ++j) oa[i][j] = 0.f;
    }

    for (int kt = 0; kt <= qt; ++kt) {
        __syncthreads();  // previous iteration fully done with Kst/Vs/Pst
        {
            const int d0 = (t & 15) * 4;
            const int rb = t >> 4;
            const int k0r = kt * BKV;
#pragma unroll
            for (int rr = 0; rr < 4; ++rr) {
                const int r = rb + rr * 16;
                float4 kv4 = *reinterpret_cast<const float4*>(&k[(size_t)(k0r + r) * DM + h * HD + d0]);
                Kst[d0 + 0][r] = kv4.x; Kst[d0 + 1][r] = kv4.y;
                Kst[d0 + 2][r] = kv4.z; Kst[d0 + 3][r] = kv4.w;
                float4 vv4 = *reinterpret_cast<const float4*>(&v[(size_t)(k0r + r) * DM + h * HD + d0]);
                *reinterpret_cast<float4*>(&Vs[r][d0]) = vv4;
            }
        }
        __syncthreads();

        // S = (Q/8) K^T  : 4x4 per thread, outer product over d
        float s[4][4];
#pragma unroll
        for (int i = 0; i < 4; ++i)
#pragma unroll
            for (int j = 0; j < 4; ++j) s[i][j] = 0.f;
#pragma unroll 4
        for (int d = 0; d < HD; ++d) {
            float a4[4], b4[4];
            *reinterpret_cast<float4*>(a4) = *reinterpret_cast<const float4*>(&Qst[d][ty * 4]);
            *reinterpret_cast<float4*>(b4) = *reinterpret_cast<const float4*>(&Kst[d][tx * 4]);
#pragma unroll
            for (int i = 0; i < 4; ++i)
#pragma unroll
                for (int j = 0; j < 4; ++j) s[i][j] += a4[i] * b4[j];
        }

        // causal mask (only the diagonal tile needs it)
        if (kt == qt) {
#pragma unroll
            for (int i = 0; i < 4; ++i) {
                const int gr = ty * 4 + i;
#pragma unroll
                for (int j = 0; j < 4; ++j)
                    if (tx * 4 + j > gr) s[i][j] = -INFINITY;
            }
        }

        // online softmax (row stats reduced across the 16 tx lanes via shfl)
#pragma unroll
        for (int i = 0; i < 4; ++i) {
            float mx = fmaxf(fmaxf(s[i][0], s[i][1]), fmaxf(s[i][2], s[i][3]));
#pragma unroll
            for (int o = 1; o < 16; o <<= 1) mx = fmaxf(mx, __shfl_xor(mx, o));
            const float mn = fmaxf(m_i[i], mx);
            const float sc = expf(m_i[i] - mn);  // 0 on first tile
            float ps = 0.f;
#pragma unroll
            for (int j = 0; j < 4; ++j) {
                const float p = expf(s[i][j] - mn);
                s[i][j] = p; ps += p;
            }
#pragma unroll
            for (int o = 1; o < 16; o <<= 1) ps += __shfl_xor(ps, o);
            l_i[i] = l_i[i] * sc + ps;
            m_i[i] = mn;
#pragma unroll
            for (int j = 0; j < 4; ++j) oa[i][j] *= sc;
        }

        // publish P transposed
#pragma unroll
        for (int j = 0; j < 4; ++j) {
            float4 pv = make_float4(s[0][j], s[1][j], s[2][j], s[3][j]);
            *reinterpret_cast<float4*>(&Pst[tx * 4 + j][ty * 4]) = pv;
        }
        __syncthreads();

        // O += P V : outer product over kv columns
#pragma unroll 4
        for (int c = 0; c < BKV; ++c) {
            float p4[4], v4[4];
            *reinterpret_cast<float4*>(p4) = *reinterpret_cast<const float4*>(&Pst[c][ty * 4]);
            *reinterpret_cast<float4*>(v4) = *reinterpret_cast<const float4*>(&Vs[c][tx * 4]);
#pragma unroll
            for (int i = 0; i < 4; ++i)
#pragma unroll
                for (int j = 0; j < 4; ++j) oa[i][j] += p4[i] * v4[j];
        }
    }

    // epilogue: normalize and store [L][NH*HD]
#pragma unroll
    for (int i = 0; i < 4; ++i) {
        const float inv = 1.0f / l_i[i];
        float4 o = make_float4(oa[i][0] * inv, oa[i][1] * inv, oa[i][2] * inv, oa[i][3] * inv);
        *reinterpret_cast<float4*>(&out[(size_t)(q0 + ty * 4 + i) * DM + h * HD + tx * 4]) = o;
    }
}

extern "C" void kernel_launch(void* const* d_in, const int* in_sizes, int n_in,
                              void* d_out, int out_size, void* d_ws, size_t ws_size,
                              hipStream_t stream) {
    const float* x  = (const float*)d_in[0];
    const float* wq = (const float*)d_in[1];
    const float* wk = (const float*)d_in[2];
    const float* wv = (const float*)d_in[3];
    const float* wo = (const float*)d_in[4];
    float* out = (float*)d_out;

    const int L = in_sizes[0] / DM;  // 4096
    const size_t NE = (size_t)L * DM;

    float* qbuf = (float*)d_ws;
    float* kbuf = qbuf + NE;
    float* vbuf = kbuf + NE;
    float* abuf = vbuf + NE;

    // projections: q/k/v = x @ W^T
    dim3 gblk(256);
    dim3 ggrid(DM / 64, L / 128);
    gemm_abt<<<ggrid, gblk, 0, stream>>>(x, wq, qbuf, L, DM, DM);
    gemm_abt<<<ggrid, gblk, 0, stream>>>(x, wk, kbuf, L, DM, DM);
    gemm_abt<<<ggrid, gblk, 0, stream>>>(x, wv, vbuf, L, DM, DM);

    // RoPE in place on q, k
    rope_kernel<<<dim3(L), dim3(512), 0, stream>>>(qbuf, kbuf);

    // causal flash attention -> abuf [L][DM]
    flash_attn<<<dim3(L / 64, NH), dim3(256), 0, stream>>>(qbuf, kbuf, vbuf, abuf, L);

    // output projection
    gemm_abt<<<ggrid, gblk, 0, stream>>>(abuf, wo, out, L, DM, DM);
}

// Round 2
// 399.169 us; speedup vs baseline: 3.9099x; 3.9099x over previous
//
#include <hip/hip_runtime.h>
#include <math.h>
#include <type_traits>

constexpr int DM = 1024;
constexpr int NH = 16;
constexpr int HD = 64;

typedef __attribute__((ext_vector_type(8))) short bf16x8;
typedef __attribute__((ext_vector_type(4))) float f32x4;

__device__ __forceinline__ unsigned short f2bf(float f) {
    union { float f; unsigned u; } v; v.f = f;
    unsigned r = v.u + 0x7FFFu + ((v.u >> 16) & 1u);
    return (unsigned short)(r >> 16);
}
__device__ __forceinline__ float bf2f(unsigned short h) {
    union { unsigned u; float f; } v; v.u = ((unsigned)h) << 16;
    return v.f;
}
__device__ __forceinline__ void gload16(const unsigned short* g, unsigned short* lds) {
    __builtin_amdgcn_global_load_lds(
        (const __attribute__((address_space(1))) unsigned int*)g,
        (__attribute__((address_space(3))) unsigned int*)lds, 16, 0, 0);
}
#define MFMA_BF16(a, b, c) __builtin_amdgcn_mfma_f32_16x16x32_bf16(a, b, c, 0, 0, 0)

// ---------------------------------------------------------------------------
// fp32 -> bf16 conversion of x and the 4 weights into one flat bf16 region.
// ---------------------------------------------------------------------------
__global__ __launch_bounds__(256)
void convert_bf16(const float* __restrict__ x, const float* __restrict__ wq,
                  const float* __restrict__ wk, const float* __restrict__ wv,
                  const float* __restrict__ wo, unsigned short* __restrict__ dst,
                  long long xElems) {
    const long long W = (long long)DM * DM;
    long long base = ((long long)blockIdx.x * 256 + threadIdx.x) * 8;
    const float* src; long long off;
    if (base < xElems) { src = x; off = base; }
    else {
        long long r = base - xElems;
        int wi = (int)(r / W); off = r - (long long)wi * W;
        src = wi == 0 ? wq : wi == 1 ? wk : wi == 2 ? wv : wo;
    }
    float4 a = *reinterpret_cast<const float4*>(src + off);
    float4 b = *reinterpret_cast<const float4*>(src + off + 4);
    uint4 o;
    o.x = (unsigned)f2bf(a.x) | ((unsigned)f2bf(a.y) << 16);
    o.y = (unsigned)f2bf(a.z) | ((unsigned)f2bf(a.w) << 16);
    o.z = (unsigned)f2bf(b.x) | ((unsigned)f2bf(b.y) << 16);
    o.w = (unsigned)f2bf(b.z) | ((unsigned)f2bf(b.w) << 16);
    *reinterpret_cast<uint4*>(dst + base) = o;
}

// ---------------------------------------------------------------------------
// bf16 MFMA GEMM: C[M][N] = A[M][K] * B[N][K]^T. 128x128 tile, BK=32, 4 waves.
// LDS linear + chunk XOR swizzle (both-sides: pre-swizzled global source via
// global_load_lds, swizzled ds_read). Wave w owns 64x64 at (w>>1, w&1).
// ---------------------------------------------------------------------------
template <typename OT>
__global__ __launch_bounds__(256)
void gemm_bf16(const unsigned short* __restrict__ A, const unsigned short* __restrict__ B,
               OT* __restrict__ C, int M, int N, int K) {
    constexpr int BK = 32;
    __shared__ unsigned short As[128 * BK];
    __shared__ unsigned short Bs[128 * BK];
    const int t = threadIdx.x;
    const int w = t >> 6, l = t & 63;
    const int lg = l >> 4, ln = l & 15;
    const int bm = blockIdx.y * 128, bn = blockIdx.x * 128;
    const int wr = (w >> 1) * 64, wc = (w & 1) * 64;

    // staging: 512 chunks of 16B per tile; chunk li -> row li>>2, phys chunk li&3
    const int li0 = t, li1 = 256 + t;
    const int r0 = li0 >> 2, c0 = (li0 & 3) ^ ((r0 >> 1) & 3);
    const int r1 = li1 >> 2, c1 = (li1 & 3) ^ ((r1 >> 1) & 3);
    const unsigned short* gA0 = A + (size_t)(bm + r0) * K + c0 * 8;
    const unsigned short* gA1 = A + (size_t)(bm + r1) * K + c1 * 8;
    const unsigned short* gB0 = B + (size_t)(bn + r0) * K + c0 * 8;
    const unsigned short* gB1 = B + (size_t)(bn + r1) * K + c1 * 8;
    unsigned short* lA0 = As + (size_t)(w * 64) * 8;
    unsigned short* lA1 = As + (size_t)(256 + w * 64) * 8;
    unsigned short* lB0 = Bs + (size_t)(w * 64) * 8;
    unsigned short* lB1 = Bs + (size_t)(256 + w * 64) * 8;

    int aoff[4], boff[4];
#pragma unroll
    for (int m = 0; m < 4; ++m) { int R = wr + m * 16 + ln; aoff[m] = R * 64 + ((lg ^ ((R >> 1) & 3)) * 16); }
#pragma unroll
    for (int n = 0; n < 4; ++n) { int R = wc + n * 16 + ln; boff[n] = R * 64 + ((lg ^ ((R >> 1) & 3)) * 16); }

    const f32x4 z4 = {0.f, 0.f, 0.f, 0.f};
    f32x4 acc[4][4];
#pragma unroll
    for (int m = 0; m < 4; ++m)
#pragma unroll
        for (int n = 0; n < 4; ++n) acc[m][n] = z4;

    for (int k0 = 0; k0 < K; k0 += BK) {
        __syncthreads();
        gload16(gA0 + k0, lA0);
        gload16(gA1 + k0, lA1);
        gload16(gB0 + k0, lB0);
        gload16(gB1 + k0, lB1);
        __syncthreads();
        bf16x8 af[4], bfr[4];
#pragma unroll
        for (int m = 0; m < 4; ++m) af[m] = *(const bf16x8*)((const char*)As + aoff[m]);
#pragma unroll
        for (int n = 0; n < 4; ++n) bfr[n] = *(const bf16x8*)((const char*)Bs + boff[n]);
#pragma unroll
        for (int m = 0; m < 4; ++m)
#pragma unroll
            for (int n = 0; n < 4; ++n)
                acc[m][n] = MFMA_BF16(af[m], bfr[n], acc[m][n]);
    }

#pragma unroll
    for (int m = 0; m < 4; ++m)
#pragma unroll
        for (int n = 0; n < 4; ++n)
#pragma unroll
            for (int rg = 0; rg < 4; ++rg) {
                int row = bm + wr + m * 16 + lg * 4 + rg;
                int col = bn + wc + n * 16 + ln;
                if constexpr (std::is_same<OT, float>::value)
                    C[(size_t)row * N + col] = acc[m][n][rg];
                else
                    C[(size_t)row * N + col] = f2bf(acc[m][n][rg]);
            }
}

// ---------------------------------------------------------------------------
// RoPE in place on bf16 q, k.
// ---------------------------------------------------------------------------
__global__ __launch_bounds__(512)
void rope_bf16(unsigned short* __restrict__ q, unsigned short* __restrict__ k) {
    const int l = blockIdx.x;
    const int j = threadIdx.x & 31, h = threadIdx.x >> 5;
    const float inv = exp2f(-(float)j * (13.287712379549449f / 32.0f));
    const float ang = (float)l * inv;
    float s, c;
    sincosf(ang, &s, &c);
    const size_t base = (size_t)l * DM + h * HD + j;
    float a = bf2f(q[base]), b = bf2f(q[base + 32]);
    q[base]      = f2bf(a * c - b * s);
    q[base + 32] = f2bf(b * c + a * s);
    a = bf2f(k[base]); b = bf2f(k[base + 32]);
    k[base]      = f2bf(a * c - b * s);
    k[base + 32] = f2bf(b * c + a * s);
}

// ---------------------------------------------------------------------------
// bf16 MFMA causal flash attention. Block: (q-tile 64 rows, head); 4 waves,
// wave w owns q rows [w*16, w*16+16). K/V tiles of 64 rows.
//  - Qs/Ks: linear, chunk-swizzled (c ^= r&7), staged via global_load_lds.
//  - Vt: transposed [d][kv], chunk-swizzled pc = k8 ^ (d&7) ^ ((d>>3)&7)
//    (conflict-free on both the b16 column writes and b128 row reads).
//  - P: padded [64][72] LDS, per-wave private.
// ---------------------------------------------------------------------------
__global__ __launch_bounds__(256)
void attn_mfma(const unsigned short* __restrict__ qb, const unsigned short* __restrict__ kb,
               const unsigned short* __restrict__ vb, unsigned short* __restrict__ ob, int nqt) {
    __shared__ unsigned short Qs[64 * 64];
    __shared__ unsigned short Ks[64 * 64];
    __shared__ unsigned short Vt[64 * 64];
    __shared__ unsigned short Ps[64][72];

    const int h = blockIdx.y;
    const int bx = blockIdx.x;
    const int qt = (bx & 1) ? (nqt - 1 - (bx >> 1)) : (bx >> 1);  // pair heavy+light
    const int q0 = qt * 64;
    const int t = threadIdx.x, w = t >> 6, l = t & 63;
    const int lg = l >> 4, ln = l & 15;

    // stage Q (swizzled linear)
    {
        const int a0 = t, a1 = 256 + t;
        const int qr0 = a0 >> 3, qc0 = (a0 & 7) ^ (qr0 & 7);
        const int qr1 = a1 >> 3, qc1 = (a1 & 7) ^ (qr1 & 7);
        gload16(qb + (size_t)(q0 + qr0) * DM + h * HD + qc0 * 8, Qs + (size_t)(w * 64) * 8);
        gload16(qb + (size_t)(q0 + qr1) * DM + h * HD + qc1 * 8, Qs + (size_t)(256 + w * 64) * 8);
    }

    // fragment LDS byte offsets (k-tile independent)
    int qoff[2], koff[4][2], voff[4][2], poff[2];
#pragma unroll
    for (int ks = 0; ks < 2; ++ks) {
        const int R = w * 16 + ln;
        qoff[ks] = R * 128 + (((ks * 4 + lg) ^ (R & 7)) * 16);
        poff[ks] = (w * 16 + ln) * 144 + (ks * 32 + lg * 8) * 2;
    }
#pragma unroll
    for (int n = 0; n < 4; ++n)
#pragma unroll
        for (int ks = 0; ks < 2; ++ks) {
            const int R = n * 16 + ln;
            koff[n][ks] = R * 128 + (((ks * 4 + lg) ^ (R & 7)) * 16);
            const int d = n * 16 + ln;
            const int pc = (ks * 4 + lg) ^ (d & 7) ^ ((d >> 3) & 7);
            voff[n][ks] = d * 128 + pc * 16;
        }

    const f32x4 z4 = {0.f, 0.f, 0.f, 0.f};
    f32x4 oa[4];
#pragma unroll
    for (int dn = 0; dn < 4; ++dn) oa[dn] = z4;
    float m_i[4] = {-INFINITY, -INFINITY, -INFINITY, -INFINITY};
    float l_i[4] = {0.f, 0.f, 0.f, 0.f};

    for (int kt = 0; kt <= qt; ++kt) {
        __syncthreads();  // previous iteration done with Ks/Vt
        const int kv0 = kt * 64;
        // stage K (swizzled linear, global_load_lds)
        {
            const int a0 = t, a1 = 256 + t;
            const int kr0 = a0 >> 3, kc0 = (a0 & 7) ^ (kr0 & 7);
            const int kr1 = a1 >> 3, kc1 = (a1 & 7) ^ (kr1 & 7);
            gload16(kb + (size_t)(kv0 + kr0) * DM + h * HD + kc0 * 8, Ks + (size_t)(w * 64) * 8);
            gload16(kb + (size_t)(kv0 + kr1) * DM + h * HD + kc1 * 8, Ks + (size_t)(256 + w * 64) * 8);
        }
        // stage V transposed (reg -> swizzled b16 writes)
#pragma unroll
        for (int it = 0; it < 2; ++it) {
            const int kv = it * 32 + w * 8 + (l >> 3);
            const int d0 = (l & 7) * 8;
            uint4 raw = *reinterpret_cast<const uint4*>(vb + (size_t)(kv0 + kv) * DM + h * HD + d0);
            unsigned rr[4] = {raw.x, raw.y, raw.z, raw.w};
            const int k8v = kv >> 3, kl = kv & 7, dh = l & 7;
#pragma unroll
            for (int j = 0; j < 8; ++j) {
                const unsigned short e = (unsigned short)((rr[j >> 1] >> ((j & 1) * 16)) & 0xFFFFu);
                const int pc = k8v ^ j ^ dh;
                Vt[(d0 + j) * 64 + pc * 8 + kl] = e;
            }
        }
        __syncthreads();

        // S = Q K^T (unscaled), per-wave 16 q-rows x 64 kv-cols
        bf16x8 aq0 = *(const bf16x8*)((const char*)Qs + qoff[0]);
        bf16x8 aq1 = *(const bf16x8*)((const char*)Qs + qoff[1]);
        f32x4 s[4];
#pragma unroll
        for (int n = 0; n < 4; ++n) {
            bf16x8 b0 = *(const bf16x8*)((const char*)Ks + koff[n][0]);
            bf16x8 b1 = *(const bf16x8*)((const char*)Ks + koff[n][1]);
            s[n] = z4;
            s[n] = MFMA_BF16(aq0, b0, s[n]);
            s[n] = MFMA_BF16(aq1, b1, s[n]);
        }
#pragma unroll
        for (int n = 0; n < 4; ++n) s[n] *= 0.125f;

        if (kt == qt) {
            const int qrow = w * 16 + lg * 4;
#pragma unroll
            for (int n = 0; n < 4; ++n)
#pragma unroll
                for (int rg = 0; rg < 4; ++rg)
                    if (n * 16 + ln > qrow + rg) s[n][rg] = -INFINITY;
        }

        // online softmax (per accumulator row rg; reduce over 16-lane group)
#pragma unroll
        for (int rg = 0; rg < 4; ++rg) {
            float mx = fmaxf(fmaxf(s[0][rg], s[1][rg]), fmaxf(s[2][rg], s[3][rg]));
            mx = fmaxf(mx, __shfl_xor(mx, 1));
            mx = fmaxf(mx, __shfl_xor(mx, 2));
            mx = fmaxf(mx, __shfl_xor(mx, 4));
            mx = fmaxf(mx, __shfl_xor(mx, 8));
            const float mn = fmaxf(m_i[rg], mx);
            const float sc = __expf(m_i[rg] - mn);
            m_i[rg] = mn;
            float ps = 0.f;
#pragma unroll
            for (int n = 0; n < 4; ++n) {
                const float p = __expf(s[n][rg] - mn);
                s[n][rg] = p; ps += p;
            }
            ps += __shfl_xor(ps, 1); ps += __shfl_xor(ps, 2);
            ps += __shfl_xor(ps, 4); ps += __shfl_xor(ps, 8);
            l_i[rg] = l_i[rg] * sc + ps;
            oa[0][rg] *= sc; oa[1][rg] *= sc; oa[2][rg] *= sc; oa[3][rg] *= sc;
        }

        // publish P (bf16) — wave-private rows, no barrier needed
#pragma unroll
        for (int n = 0; n < 4; ++n)
#pragma unroll
            for (int rg = 0; rg < 4; ++rg)
                Ps[w * 16 + lg * 4 + rg][n * 16 + ln] = f2bf(s[n][rg]);

        // O += P V
        bf16x8 pa0 = *(const bf16x8*)((const char*)Ps + poff[0]);
        bf16x8 pa1 = *(const bf16x8*)((const char*)Ps + poff[1]);
#pragma unroll
        for (int dn = 0; dn < 4; ++dn) {
            bf16x8 v0 = *(const bf16x8*)((const char*)Vt + voff[dn][0]);
            bf16x8 v1 = *(const bf16x8*)((const char*)Vt + voff[dn][1]);
            oa[dn] = MFMA_BF16(pa0, v0, oa[dn]);
            oa[dn] = MFMA_BF16(pa1, v1, oa[dn]);
        }
    }

    // epilogue: normalize, bf16 store
#pragma unroll
    for (int rg = 0; rg < 4; ++rg) {
        const float inv = 1.f / l_i[rg];
        const int row = q0 + w * 16 + lg * 4 + rg;
#pragma unroll
        for (int dn = 0; dn < 4; ++dn)
            ob[(size_t)row * DM + h * HD + dn * 16 + ln] = f2bf(oa[dn][rg] * inv);
    }
}

extern "C" void kernel_launch(void* const* d_in, const int* in_sizes, int n_in,
                              void* d_out, int out_size, void* d_ws, size_t ws_size,
                              hipStream_t stream) {
    const float* x  = (const float*)d_in[0];
    const float* wq = (const float*)d_in[1];
    const float* wk = (const float*)d_in[2];
    const float* wv = (const float*)d_in[3];
    const float* wo = (const float*)d_in[4];

    const int L = in_sizes[0] / DM;          // 4096
    const size_t NE = (size_t)L * DM;        // 4M
    const size_t W  = (size_t)DM * DM;       // 1M

    unsigned short* xb  = (unsigned short*)d_ws;
    unsigned short* wqb = xb + NE;
    unsigned short* wkb = wqb + W;
    unsigned short* wvb = wkb + W;
    unsigned short* wob = wvb + W;
    unsigned short* qbb = wob + W;
    unsigned short* kbb = qbb + NE;
    unsigned short* vbb = kbb + NE;
    unsigned short* ab  = vbb + NE;

    const long long totalConv = (long long)(NE + 4 * W);  // 8M
    convert_bf16<<<dim3((unsigned)(totalConv / 8 / 256)), dim3(256), 0, stream>>>(
        x, wq, wk, wv, wo, xb, (long long)NE);

    dim3 gg(DM / 128, L / 128);  // (8, 32)
    gemm_bf16<unsigned short><<<gg, dim3(256), 0, stream>>>(xb, wqb, qbb, L, DM, DM);
    gemm_bf16<unsigned short><<<gg, dim3(256), 0, stream>>>(xb, wkb, kbb, L, DM, DM);
    gemm_bf16<unsigned short><<<gg, dim3(256), 0, stream>>>(xb, wvb, vbb, L, DM, DM);

    rope_bf16<<<dim3(L), dim3(512), 0, stream>>>(qbb, kbb);

    attn_mfma<<<dim3(L / 64, NH), dim3(256), 0, stream>>>(qbb, kbb, vbb, ab, L / 64);

    gemm_bf16<float><<<gg, dim3(256), 0, stream>>>(ab, wob, (float*)d_out, L, DM, DM);
}

// Round 4
// 219.232 us; speedup vs baseline: 7.1190x; 1.8208x over previous
//
#include <hip/hip_runtime.h>
#include <math.h>
#include <type_traits>

constexpr int DM = 1024;
constexpr int NH = 16;
constexpr int HD = 64;
constexpr int LDQ = 3072;  // fused qkv row stride

typedef __attribute__((ext_vector_type(8))) short bf16x8;
typedef __attribute__((ext_vector_type(4))) float f32x4;

__device__ __forceinline__ unsigned short f2bf(float f) {
    union { float f; unsigned u; } v; v.f = f;
    unsigned r = v.u + 0x7FFFu + ((v.u >> 16) & 1u);
    return (unsigned short)(r >> 16);
}
__device__ __forceinline__ float bf2f(unsigned short h) {
    union { unsigned u; float f; } v; v.u = ((unsigned)h) << 16;
    return v.f;
}
__device__ __forceinline__ void gload16(const unsigned short* g, unsigned short* lds) {
    __builtin_amdgcn_global_load_lds(
        (const __attribute__((address_space(1))) unsigned int*)g,
        (__attribute__((address_space(3))) unsigned int*)lds, 16, 0, 0);
}
__device__ __forceinline__ unsigned cvt_pk_bf16(float lo, float hi) {
    unsigned r;
    asm("v_cvt_pk_bf16_f32 %0, %1, %2" : "=v"(r) : "v"(lo), "v"(hi));
    return r;
}
#define MFMA_BF16(a, b, c) __builtin_amdgcn_mfma_f32_16x16x32_bf16(a, b, c, 0, 0, 0)

// ---------------------------------------------------------------------------
// fp32 -> bf16 conversion of x and the 4 weights into one flat bf16 region.
// ---------------------------------------------------------------------------
__global__ __launch_bounds__(256)
void convert_bf16(const float* __restrict__ x, const float* __restrict__ wq,
                  const float* __restrict__ wk, const float* __restrict__ wv,
                  const float* __restrict__ wo, unsigned short* __restrict__ dst,
                  long long xElems) {
    const long long W = (long long)DM * DM;
    long long base = ((long long)blockIdx.x * 256 + threadIdx.x) * 8;
    const float* src; long long off;
    if (base < xElems) { src = x; off = base; }
    else {
        long long r = base - xElems;
        int wi = (int)(r / W); off = r - (long long)wi * W;
        src = wi == 0 ? wq : wi == 1 ? wk : wi == 2 ? wv : wo;
    }
    float4 a = *reinterpret_cast<const float4*>(src + off);
    float4 b = *reinterpret_cast<const float4*>(src + off + 4);
    uint4 o;
    o.x = (unsigned)f2bf(a.x) | ((unsigned)f2bf(a.y) << 16);
    o.y = (unsigned)f2bf(a.z) | ((unsigned)f2bf(a.w) << 16);
    o.z = (unsigned)f2bf(b.x) | ((unsigned)f2bf(b.y) << 16);
    o.w = (unsigned)f2bf(b.z) | ((unsigned)f2bf(b.w) << 16);
    *reinterpret_cast<uint4*>(dst + base) = o;
}

// ---------------------------------------------------------------------------
// bf16 MFMA GEMM: C[M][N] = A[M][K] * B[N][K]^T. 128x128 tile, BK=32, 4 waves.
// aoff/boff are BYTE offsets (row stride 64 B = BK bf16).
// ---------------------------------------------------------------------------
template <typename OT>
__global__ __launch_bounds__(256)
void gemm_bf16(const unsigned short* __restrict__ A, const unsigned short* __restrict__ B,
               OT* __restrict__ C, int M, int N, int K) {
    constexpr int BK = 32;
    __shared__ unsigned short As[128 * BK];
    __shared__ unsigned short Bs[128 * BK];
    const int t = threadIdx.x;
    const int w = t >> 6, l = t & 63;
    const int lg = l >> 4, ln = l & 15;
    const int bm = blockIdx.y * 128, bn = blockIdx.x * 128;
    const int wr = (w >> 1) * 64, wc = (w & 1) * 64;

    const int li0 = t, li1 = 256 + t;
    const int r0 = li0 >> 2, c0 = (li0 & 3) ^ ((r0 >> 1) & 3);
    const int r1 = li1 >> 2, c1 = (li1 & 3) ^ ((r1 >> 1) & 3);
    const unsigned short* gA0 = A + (size_t)(bm + r0) * K + c0 * 8;
    const unsigned short* gA1 = A + (size_t)(bm + r1) * K + c1 * 8;
    const unsigned short* gB0 = B + (size_t)(bn + r0) * K + c0 * 8;
    const unsigned short* gB1 = B + (size_t)(bn + r1) * K + c1 * 8;
    unsigned short* lA0 = As + (size_t)(w * 64) * 8;
    unsigned short* lA1 = As + (size_t)(256 + w * 64) * 8;
    unsigned short* lB0 = Bs + (size_t)(w * 64) * 8;
    unsigned short* lB1 = Bs + (size_t)(256 + w * 64) * 8;

    int aoff[4], boff[4];  // BYTE offsets
#pragma unroll
    for (int m = 0; m < 4; ++m) { int R = wr + m * 16 + ln; aoff[m] = R * 64 + ((lg ^ ((R >> 1) & 3)) * 16); }
#pragma unroll
    for (int n = 0; n < 4; ++n) { int R = wc + n * 16 + ln; boff[n] = R * 64 + ((lg ^ ((R >> 1) & 3)) * 16); }

    const f32x4 z4 = {0.f, 0.f, 0.f, 0.f};
    f32x4 acc[4][4];
#pragma unroll
    for (int m = 0; m < 4; ++m)
#pragma unroll
        for (int n = 0; n < 4; ++n) acc[m][n] = z4;

    for (int k0 = 0; k0 < K; k0 += BK) {
        __syncthreads();
        gload16(gA0 + k0, lA0);
        gload16(gA1 + k0, lA1);
        gload16(gB0 + k0, lB0);
        gload16(gB1 + k0, lB1);
        __syncthreads();
        bf16x8 af[4], bfr[4];
#pragma unroll
        for (int m = 0; m < 4; ++m) af[m] = *(const bf16x8*)((const char*)As + aoff[m]);
#pragma unroll
        for (int n = 0; n < 4; ++n) bfr[n] = *(const bf16x8*)((const char*)Bs + boff[n]);
#pragma unroll
        for (int m = 0; m < 4; ++m)
#pragma unroll
            for (int n = 0; n < 4; ++n)
                acc[m][n] = MFMA_BF16(af[m], bfr[n], acc[m][n]);
    }

#pragma unroll
    for (int m = 0; m < 4; ++m)
#pragma unroll
        for (int n = 0; n < 4; ++n)
#pragma unroll
            for (int rg = 0; rg < 4; ++rg) {
                int row = bm + wr + m * 16 + lg * 4 + rg;
                int col = bn + wc + n * 16 + ln;
                if constexpr (std::is_same<OT, float>::value)
                    C[(size_t)row * N + col] = acc[m][n][rg];
                else
                    C[(size_t)row * N + col] = f2bf(acc[m][n][rg]);
            }
}

// ---------------------------------------------------------------------------
// RoPE in place on fused qkv (q at col 0, k at col 1024).
// ---------------------------------------------------------------------------
__global__ __launch_bounds__(512)
void rope_bf16(unsigned short* __restrict__ qkv) {
    const int l = blockIdx.x;
    const int j = threadIdx.x & 31, h = threadIdx.x >> 5;
    const float inv = exp2f(-(float)j * (13.287712379549449f / 32.0f));
    const float ang = (float)l * inv;
    float s, c;
    sincosf(ang, &s, &c);
    const size_t base = (size_t)l * LDQ + h * HD + j;
    float a = bf2f(qkv[base]), b = bf2f(qkv[base + 32]);
    qkv[base]      = f2bf(a * c - b * s);
    qkv[base + 32] = f2bf(b * c + a * s);
    a = bf2f(qkv[base + DM]); b = bf2f(qkv[base + DM + 32]);
    qkv[base + DM]      = f2bf(a * c - b * s);
    qkv[base + DM + 32] = f2bf(b * c + a * s);
}

// ---------------------------------------------------------------------------
// bf16 MFMA causal flash attention, swapped-operand form.
// Block = 128 q-rows x 1 head; 4 waves x 32 q-rows. K/V tiles of 64 rows,
// double-buffered, 1 barrier/tile. Q in registers from global.
// QK^T computed as mfma(K,Q) -> S^T (lane owns q-col), softmax reduce = 2 shfl.
// P packed to LDS via v_cvt_pk_bf16_f32 (b64 writes). PV computed as
// O^T = mfma(V^T, P). V transposed in regs (v_perm 2-kv packing) into LDS with
// XOR swizzle conflict-free on b32 writes and b128 reads.
// ---------------------------------------------------------------------------
__global__ __launch_bounds__(256)
void attn_mfma(const unsigned short* __restrict__ qkv, unsigned short* __restrict__ ob,
               int nqb) {
    __shared__ unsigned short Ks[2 * 4096];
    __shared__ unsigned Vt[2 * 2048];
    __shared__ unsigned short Ps[128 * 72];

    const int bid = blockIdx.x;
    const int h = bid & (NH - 1);
    const int qb = nqb - 1 - (bid >> 4);  // heavy blocks first
    const int q0 = qb * 128;
    const int t = threadIdx.x, w = t >> 6, l = t & 63;
    const int lg = l >> 4, ln = l & 15;
    const int wq0 = w * 32;

    const unsigned short* qg = qkv;
    const unsigned short* kg = qkv + DM;
    const unsigned short* vg = qkv + 2 * DM;

    // Q fragments in registers (B-operand of swapped QK^T)
    bf16x8 qf[2][2];
#pragma unroll
    for (int m = 0; m < 2; ++m)
#pragma unroll
        for (int ks = 0; ks < 2; ++ks)
            qf[m][ks] = *reinterpret_cast<const bf16x8*>(
                qg + (size_t)(q0 + wq0 + m * 16 + ln) * LDQ + h * HD + ks * 32 + lg * 8);

    // K staging (global_load_lds, chunk-swizzled source, linear LDS dest)
    const int a1 = 256 + t;
    const int r0 = t >> 3,  c0 = (t & 7) ^ (r0 & 7);
    const int r1 = a1 >> 3, c1 = (a1 & 7) ^ (r1 & 7);
    const unsigned short* kg0 = kg + (size_t)r0 * LDQ + h * HD + c0 * 8;
    const unsigned short* kg1 = kg + (size_t)r1 * LDQ + h * HD + c1 * 8;
    unsigned short* lk0 = Ks + w * 512;
    unsigned short* lk1 = Ks + 2048 + w * 512;

    // V staging: thread owns kv pair (2jj,2jj+1) x 8 d; transposed b32 writes
    const int jj = t >> 3, dcv = t & 7;
    const unsigned short* vg0 = vg + (size_t)(2 * jj) * LDQ + h * HD + dcv * 8;
    const unsigned short* vg1 = vg + (size_t)(2 * jj + 1) * LDQ + h * HD + dcv * 8;
    int vtw[8];
#pragma unroll
    for (int e = 0; e < 8; ++e) {
        const int d = dcv * 8 + e;
        const int msk = ((d & 7) ^ (d >> 3)) & 7;
        vtw[e] = d * 32 + (jj ^ (msk << 2));
    }

    // fragment read byte-offsets (tile-invariant)
    int koff[4][2], voff[4][2];
#pragma unroll
    for (int n = 0; n < 4; ++n)
#pragma unroll
        for (int ks = 0; ks < 2; ++ks) {
            const int R = n * 16 + ln;
            koff[n][ks] = R * 128 + (((ks * 4 + lg) ^ (R & 7)) * 16);
            const int d = n * 16 + ln;
            const int msk = ((d & 7) ^ (d >> 3)) & 7;
            voff[n][ks] = (d * 32 + ((ks * 16 + lg * 4) ^ (msk << 2))) * 4;
        }
    int prow[2];
#pragma unroll
    for (int m = 0; m < 2; ++m) prow[m] = (wq0 + m * 16 + ln) * 144;

    const f32x4 z4 = {0.f, 0.f, 0.f, 0.f};
    f32x4 oa[2][4];
#pragma unroll
    for (int m = 0; m < 2; ++m)
#pragma unroll
        for (int dn = 0; dn < 4; ++dn) oa[m][dn] = z4;
    float m_i[2] = {-INFINITY, -INFINITY};
    float l_i[2] = {0.f, 0.f};

    const int ntiles = 2 * qb + 2;
    const int wqmax = q0 + wq0 + 31;

    // prologue: stage tile 0 into buffer 0
    gload16(kg0, lk0);
    gload16(kg1, lk1);
    {
        uint4 va = *reinterpret_cast<const uint4*>(vg0);
        uint4 vb = *reinterpret_cast<const uint4*>(vg1);
        const unsigned aw[4] = {va.x, va.y, va.z, va.w};
        const unsigned bw[4] = {vb.x, vb.y, vb.z, vb.w};
#pragma unroll
        for (int wv = 0; wv < 4; ++wv) {
            Vt[vtw[wv * 2]]     = __builtin_amdgcn_perm(bw[wv], aw[wv], 0x05040100u);
            Vt[vtw[wv * 2 + 1]] = __builtin_amdgcn_perm(bw[wv], aw[wv], 0x07060302u);
        }
    }
    __syncthreads();

    for (int kt = 0; kt < ntiles; ++kt) {
        const int bsel = kt & 1;
        const int kv0 = kt * 64;
        const char* KsB = (const char*)Ks + bsel * 8192;
        const char* VtB = (const char*)Vt + bsel * 8192;

        uint4 pva, pvb;
        const bool pf = (kt + 1 < ntiles);
        if (pf) {  // issue next-tile staging before compute (T3)
            const size_t adv = (size_t)(kt + 1) * 64 * LDQ;
            gload16(kg0 + adv, lk0 + (bsel ^ 1) * 4096);
            gload16(kg1 + adv, lk1 + (bsel ^ 1) * 4096);
            pva = *reinterpret_cast<const uint4*>(vg0 + adv);
            pvb = *reinterpret_cast<const uint4*>(vg1 + adv);
        }

        if (kv0 <= wqmax) {  // wave-uniform skip of fully-masked tiles
            // S^T[m][n] = mfma(K, Q): rows = kv, cols = q
            bf16x8 kf[4][2];
#pragma unroll
            for (int n = 0; n < 4; ++n)
#pragma unroll
                for (int ks = 0; ks < 2; ++ks)
                    kf[n][ks] = *reinterpret_cast<const bf16x8*>(KsB + koff[n][ks]);
            f32x4 s[2][4];
#pragma unroll
            for (int m = 0; m < 2; ++m)
#pragma unroll
                for (int n = 0; n < 4; ++n) {
                    f32x4 acc = MFMA_BF16(kf[n][0], qf[m][0], z4);
                    s[m][n] = MFMA_BF16(kf[n][1], qf[m][1], acc);
                }

            constexpr float SC = 0.18033688011112042f;  // log2(e)/8
#pragma unroll
            for (int m = 0; m < 2; ++m) {
                const int qq = q0 + wq0 + m * 16 + ln;
#pragma unroll
                for (int n = 0; n < 4; ++n) s[m][n] *= SC;
                if (kv0 + 63 > q0 + wq0 + m * 16) {
#pragma unroll
                    for (int n = 0; n < 4; ++n)
#pragma unroll
                        for (int rg = 0; rg < 4; ++rg)
                            if (kv0 + n * 16 + lg * 4 + rg > qq) s[m][n][rg] = -INFINITY;
                }
            }

            // online softmax per q-column (lane-local 16 values + 2 shfl)
#pragma unroll
            for (int m = 0; m < 2; ++m) {
                float mx = fmaxf(fmaxf(s[m][0][0], s[m][0][1]), fmaxf(s[m][0][2], s[m][0][3]));
#pragma unroll
                for (int n = 1; n < 4; ++n)
                    mx = fmaxf(mx, fmaxf(fmaxf(s[m][n][0], s[m][n][1]),
                                         fmaxf(s[m][n][2], s[m][n][3])));
                mx = fmaxf(mx, __shfl_xor(mx, 16));
                mx = fmaxf(mx, __shfl_xor(mx, 32));
                const float mn = fmaxf(m_i[m], mx);
                const float sc = exp2f(m_i[m] - mn);
                m_i[m] = mn;
                float ps = 0.f;
#pragma unroll
                for (int n = 0; n < 4; ++n)
#pragma unroll
                    for (int rg = 0; rg < 4; ++rg) {
                        const float p = exp2f(s[m][n][rg] - mn);
                        s[m][n][rg] = p;
                        ps += p;
                    }
                ps += __shfl_xor(ps, 16);
                ps += __shfl_xor(ps, 32);
                l_i[m] = l_i[m] * sc + ps;
#pragma unroll
                for (int dn = 0; dn < 4; ++dn) oa[m][dn] *= sc;
                // publish P (wave-private rows, b64 packed writes)
#pragma unroll
                for (int n = 0; n < 4; ++n) {
                    const unsigned u0 = cvt_pk_bf16(s[m][n][0], s[m][n][1]);
                    const unsigned u1 = cvt_pk_bf16(s[m][n][2], s[m][n][3]);
                    *reinterpret_cast<uint2*>((char*)Ps + prow[m] + n * 32 + lg * 8) =
                        make_uint2(u0, u1);
                }
            }

            // O^T += mfma(V^T, P)
            bf16x8 vf[4][2], pfr[2][2];
#pragma unroll
            for (int dn = 0; dn < 4; ++dn)
#pragma unroll
                for (int ks = 0; ks < 2; ++ks)
                    vf[dn][ks] = *reinterpret_cast<const bf16x8*>(VtB + voff[dn][ks]);
#pragma unroll
            for (int m = 0; m < 2; ++m)
#pragma unroll
                for (int ks = 0; ks < 2; ++ks)
                    pfr[m][ks] = *reinterpret_cast<const bf16x8*>(
                        (const char*)Ps + prow[m] + ks * 64 + lg * 16);
#pragma unroll
            for (int m = 0; m < 2; ++m)
#pragma unroll
                for (int dn = 0; dn < 4; ++dn) {
                    oa[m][dn] = MFMA_BF16(vf[dn][0], pfr[m][0], oa[m][dn]);
                    oa[m][dn] = MFMA_BF16(vf[dn][1], pfr[m][1], oa[m][dn]);
                }
        }

        if (pf) {  // late V transpose-write into the other buffer
            unsigned* VtN = Vt + (bsel ^ 1) * 2048;
            const unsigned aw[4] = {pva.x, pva.y, pva.z, pva.w};
            const unsigned bw[4] = {pvb.x, pvb.y, pvb.z, pvb.w};
#pragma unroll
            for (int wv = 0; wv < 4; ++wv) {
                VtN[vtw[wv * 2]]     = __builtin_amdgcn_perm(bw[wv], aw[wv], 0x05040100u);
                VtN[vtw[wv * 2 + 1]] = __builtin_amdgcn_perm(bw[wv], aw[wv], 0x07060302u);
            }
        }
        __syncthreads();  // single barrier per tile (drains vmcnt + lgkm)
    }

    // epilogue: normalize, transpose O^T -> O via reused Ps, coalesced store
#pragma unroll
    for (int m = 0; m < 2; ++m) {
        const float inv = 1.f / l_i[m];
#pragma unroll
        for (int dn = 0; dn < 4; ++dn) {
            f32x4 o = oa[m][dn] * inv;
            const unsigned u0 = cvt_pk_bf16(o[0], o[1]);
            const unsigned u1 = cvt_pk_bf16(o[2], o[3]);
            *reinterpret_cast<uint2*>((char*)Ps + prow[m] + dn * 32 + lg * 8) =
                make_uint2(u0, u1);
        }
    }
    __syncthreads();
#pragma unroll
    for (int it = 0; it < 4; ++it) {
        const int a = it * 256 + t;
        const int r = a >> 3, c = (a & 7) * 8;
        const bf16x8 vv = *reinterpret_cast<const bf16x8*>((const char*)Ps + r * 144 + c * 2);
        *reinterpret_cast<bf16x8*>(ob + (size_t)(q0 + r) * DM + h * HD + c) = vv;
    }
}

extern "C" void kernel_launch(void* const* d_in, const int* in_sizes, int n_in,
                              void* d_out, int out_size, void* d_ws, size_t ws_size,
                              hipStream_t stream) {
    const float* x  = (const float*)d_in[0];
    const float* wq = (const float*)d_in[1];
    const float* wk = (const float*)d_in[2];
    const float* wv = (const float*)d_in[3];
    const float* wo = (const float*)d_in[4];

    const int L = in_sizes[0] / DM;          // 4096
    const size_t NE = (size_t)L * DM;        // 4M
    const size_t W  = (size_t)DM * DM;       // 1M

    unsigned short* xb   = (unsigned short*)d_ws;
    unsigned short* wqb  = xb + NE;          // wq|wk|wv contiguous for fused GEMM
    unsigned short* wob  = wqb + 3 * W;
    unsigned short* qkvb = wob + W;          // [L][3072]
    unsigned short* ab   = qkvb + (size_t)L * LDQ;

    const long long totalConv = (long long)(NE + 4 * W);  // 8M
    convert_bf16<<<dim3((unsigned)(totalConv / 8 / 256)), dim3(256), 0, stream>>>(
        x, wq, wk, wv, wo, xb, (long long)NE);

    // fused q|k|v projection: C[L][3072] = x @ [wq;wk;wv]^T
    gemm_bf16<unsigned short><<<dim3(LDQ / 128, L / 128), dim3(256), 0, stream>>>(
        xb, wqb, qkvb, L, LDQ, DM);

    rope_bf16<<<dim3(L), dim3(512), 0, stream>>>(qkvb);

    attn_mfma<<<dim3((L / 128) * NH), dim3(256), 0, stream>>>(qkvb, ab, L / 128);

    gemm_bf16<float><<<dim3(DM / 128, L / 128), dim3(256), 0, stream>>>(
        ab, wob, (float*)d_out, L, DM, DM);
}

// Round 5
// 181.412 us; speedup vs baseline: 8.6031x; 1.2085x over previous
//
#include <hip/hip_runtime.h>
#include <math.h>
#include <type_traits>

constexpr int DM = 1024;
constexpr int NH = 16;
constexpr int HD = 64;
constexpr int LDQ = 3072;  // fused qkv row stride

typedef __attribute__((ext_vector_type(8))) short bf16x8;
typedef __attribute__((ext_vector_type(4))) float f32x4;

__device__ __forceinline__ unsigned short f2bf(float f) {
    union { float f; unsigned u; } v; v.f = f;
    unsigned r = v.u + 0x7FFFu + ((v.u >> 16) & 1u);
    return (unsigned short)(r >> 16);
}
__device__ __forceinline__ float bf2f(unsigned short h) {
    union { unsigned u; float f; } v; v.u = ((unsigned)h) << 16;
    return v.f;
}
__device__ __forceinline__ void gload16(const unsigned short* g, unsigned short* lds) {
    __builtin_amdgcn_global_load_lds(
        (const __attribute__((address_space(1))) unsigned int*)g,
        (__attribute__((address_space(3))) unsigned int*)lds, 16, 0, 0);
}
__device__ __forceinline__ unsigned cvt_pk_bf16(float lo, float hi) {
    unsigned r;
    asm("v_cvt_pk_bf16_f32 %0, %1, %2" : "=v"(r) : "v"(lo), "v"(hi));
    return r;
}
#define MFMA_BF16(a, b, c) __builtin_amdgcn_mfma_f32_16x16x32_bf16(a, b, c, 0, 0, 0)

// In-register P redistribution (T12): takes two adjacent 16-kv S^T slices
// (lane layout: q=ln, kv=n*16+lg*4+rg) and produces the PV B-operand fragment
// (lane layout: q=ln, kv=32-block with k=lg*8+j). perm32 then perm16 swap.
__device__ __forceinline__ bf16x8 pack_swap(const f32x4& s0, const f32x4& s1) {
    unsigned c00 = cvt_pk_bf16(s0[0], s0[1]);
    unsigned c01 = cvt_pk_bf16(s0[2], s0[3]);
    unsigned c10 = cvt_pk_bf16(s1[0], s1[1]);
    unsigned c11 = cvt_pk_bf16(s1[2], s1[3]);
    asm("v_permlane32_swap_b32 %0, %1" : "+v"(c00), "+v"(c10));
    asm("v_permlane16_swap_b32 %0, %1" : "+v"(c00), "+v"(c10));
    asm("v_permlane32_swap_b32 %0, %1" : "+v"(c01), "+v"(c11));
    asm("v_permlane16_swap_b32 %0, %1" : "+v"(c01), "+v"(c11));
    union { unsigned u[4]; bf16x8 b; } r;
    r.u[0] = c00; r.u[1] = c01; r.u[2] = c10; r.u[3] = c11;
    return r.b;
}

// ---------------------------------------------------------------------------
// fp32 -> bf16 conversion of x and the 4 weights into one flat bf16 region.
// ---------------------------------------------------------------------------
__global__ __launch_bounds__(256)
void convert_bf16(const float* __restrict__ x, const float* __restrict__ wq,
                  const float* __restrict__ wk, const float* __restrict__ wv,
                  const float* __restrict__ wo, unsigned short* __restrict__ dst,
                  long long xElems) {
    const long long W = (long long)DM * DM;
    long long base = ((long long)blockIdx.x * 256 + threadIdx.x) * 8;
    const float* src; long long off;
    if (base < xElems) { src = x; off = base; }
    else {
        long long r = base - xElems;
        int wi = (int)(r / W); off = r - (long long)wi * W;
        src = wi == 0 ? wq : wi == 1 ? wk : wi == 2 ? wv : wo;
    }
    float4 a = *reinterpret_cast<const float4*>(src + off);
    float4 b = *reinterpret_cast<const float4*>(src + off + 4);
    uint4 o;
    o.x = (unsigned)f2bf(a.x) | ((unsigned)f2bf(a.y) << 16);
    o.y = (unsigned)f2bf(a.z) | ((unsigned)f2bf(a.w) << 16);
    o.z = (unsigned)f2bf(b.x) | ((unsigned)f2bf(b.y) << 16);
    o.w = (unsigned)f2bf(b.z) | ((unsigned)f2bf(b.w) << 16);
    *reinterpret_cast<uint4*>(dst + base) = o;
}

// ---------------------------------------------------------------------------
// bf16 MFMA GEMM: C[M][N] = A[M][K] * B[N][K]^T. 128x128 tile, BK=32, 4 waves.
// aoff/boff are BYTE offsets (row stride 64 B = BK bf16).
// ---------------------------------------------------------------------------
template <typename OT>
__global__ __launch_bounds__(256)
void gemm_bf16(const unsigned short* __restrict__ A, const unsigned short* __restrict__ B,
               OT* __restrict__ C, int M, int N, int K) {
    constexpr int BK = 32;
    __shared__ unsigned short As[128 * BK];
    __shared__ unsigned short Bs[128 * BK];
    const int t = threadIdx.x;
    const int w = t >> 6, l = t & 63;
    const int lg = l >> 4, ln = l & 15;
    const int bm = blockIdx.y * 128, bn = blockIdx.x * 128;
    const int wr = (w >> 1) * 64, wc = (w & 1) * 64;

    const int li0 = t, li1 = 256 + t;
    const int r0 = li0 >> 2, c0 = (li0 & 3) ^ ((r0 >> 1) & 3);
    const int r1 = li1 >> 2, c1 = (li1 & 3) ^ ((r1 >> 1) & 3);
    const unsigned short* gA0 = A + (size_t)(bm + r0) * K + c0 * 8;
    const unsigned short* gA1 = A + (size_t)(bm + r1) * K + c1 * 8;
    const unsigned short* gB0 = B + (size_t)(bn + r0) * K + c0 * 8;
    const unsigned short* gB1 = B + (size_t)(bn + r1) * K + c1 * 8;
    unsigned short* lA0 = As + (size_t)(w * 64) * 8;
    unsigned short* lA1 = As + (size_t)(256 + w * 64) * 8;
    unsigned short* lB0 = Bs + (size_t)(w * 64) * 8;
    unsigned short* lB1 = Bs + (size_t)(256 + w * 64) * 8;

    int aoff[4], boff[4];  // BYTE offsets
#pragma unroll
    for (int m = 0; m < 4; ++m) { int R = wr + m * 16 + ln; aoff[m] = R * 64 + ((lg ^ ((R >> 1) & 3)) * 16); }
#pragma unroll
    for (int n = 0; n < 4; ++n) { int R = wc + n * 16 + ln; boff[n] = R * 64 + ((lg ^ ((R >> 1) & 3)) * 16); }

    const f32x4 z4 = {0.f, 0.f, 0.f, 0.f};
    f32x4 acc[4][4];
#pragma unroll
    for (int m = 0; m < 4; ++m)
#pragma unroll
        for (int n = 0; n < 4; ++n) acc[m][n] = z4;

    for (int k0 = 0; k0 < K; k0 += BK) {
        __syncthreads();
        gload16(gA0 + k0, lA0);
        gload16(gA1 + k0, lA1);
        gload16(gB0 + k0, lB0);
        gload16(gB1 + k0, lB1);
        __syncthreads();
        bf16x8 af[4], bfr[4];
#pragma unroll
        for (int m = 0; m < 4; ++m) af[m] = *(const bf16x8*)((const char*)As + aoff[m]);
#pragma unroll
        for (int n = 0; n < 4; ++n) bfr[n] = *(const bf16x8*)((const char*)Bs + boff[n]);
#pragma unroll
        for (int m = 0; m < 4; ++m)
#pragma unroll
            for (int n = 0; n < 4; ++n)
                acc[m][n] = MFMA_BF16(af[m], bfr[n], acc[m][n]);
    }

#pragma unroll
    for (int m = 0; m < 4; ++m)
#pragma unroll
        for (int n = 0; n < 4; ++n)
#pragma unroll
            for (int rg = 0; rg < 4; ++rg) {
                int row = bm + wr + m * 16 + lg * 4 + rg;
                int col = bn + wc + n * 16 + ln;
                if constexpr (std::is_same<OT, float>::value)
                    C[(size_t)row * N + col] = acc[m][n][rg];
                else
                    C[(size_t)row * N + col] = f2bf(acc[m][n][rg]);
            }
}

// ---------------------------------------------------------------------------
// RoPE in place on fused qkv (q at col 0, k at col 1024).
// Q additionally scaled by log2(e)/8 so attention scores are exp2-ready.
// ---------------------------------------------------------------------------
__global__ __launch_bounds__(512)
void rope_bf16(unsigned short* __restrict__ qkv) {
    constexpr float SCQ = 0.18033688011112042f;  // log2(e)/sqrt(64)
    const int l = blockIdx.x;
    const int j = threadIdx.x & 31, h = threadIdx.x >> 5;
    const float inv = exp2f(-(float)j * (13.287712379549449f / 32.0f));
    const float ang = (float)l * inv;
    float s, c;
    sincosf(ang, &s, &c);
    const size_t base = (size_t)l * LDQ + h * HD + j;
    float a = bf2f(qkv[base]), b = bf2f(qkv[base + 32]);
    qkv[base]      = f2bf((a * c - b * s) * SCQ);
    qkv[base + 32] = f2bf((b * c + a * s) * SCQ);
    a = bf2f(qkv[base + DM]); b = bf2f(qkv[base + DM + 32]);
    qkv[base + DM]      = f2bf(a * c - b * s);
    qkv[base + DM + 32] = f2bf(b * c + a * s);
}

// ---------------------------------------------------------------------------
// bf16 MFMA causal flash attention, swapped-operand form, balanced pairing.
// Block = (pair p, head h): processes q-strip (nst-1-p) then strip p, each
// 64 rows -> uniform 65 tile-iterations per block. 4 waves x 16 q-rows.
// K/V tiles of 64 rows, double-buffered, 1 barrier/tile.
// QK^T = mfma(K,Q) -> S^T; softmax lane-local + 2 shfl; defer-max (THR=8,
// log2 domain). P redistributed fully in-register via cvt_pk + permlane
// swaps (no LDS round-trip). PV: O^T = mfma(V^T, P). Epilogue transposes
// O^T through small LDS for coalesced bf16 stores.
// ---------------------------------------------------------------------------
__global__ __launch_bounds__(256)
void attn_mfma(const unsigned short* __restrict__ qkv,
               unsigned short* __restrict__ ob, int nst) {
    __shared__ unsigned short Ks[2 * 4096];
    __shared__ unsigned Vt[2 * 2048];
    __shared__ unsigned short Ps[64 * 72];

    const int p = blockIdx.x;          // pair index 0..nst/2-1
    const int h = blockIdx.y;          // head
    const int t = threadIdx.x, w = t >> 6, l = t & 63;
    const int lg = l >> 4, ln = l & 15;

    const unsigned short* qg = qkv;
    const unsigned short* kg = qkv + DM;
    const unsigned short* vg = qkv + 2 * DM;

    // K staging addresses (kv-tile-relative, phase-invariant)
    const int a1 = 256 + t;
    const int r0 = t >> 3,  c0 = (t & 7) ^ (r0 & 7);
    const int r1 = a1 >> 3, c1 = (a1 & 7) ^ (r1 & 7);
    const unsigned short* kg0 = kg + (size_t)r0 * LDQ + h * HD + c0 * 8;
    const unsigned short* kg1 = kg + (size_t)r1 * LDQ + h * HD + c1 * 8;
    unsigned short* lk0 = Ks + w * 512;
    unsigned short* lk1 = Ks + 2048 + w * 512;

    // V staging: thread owns kv pair (2jj,2jj+1) x 8 d; transposed b32 writes
    const int jj = t >> 3, dcv = t & 7;
    const unsigned short* vg0 = vg + (size_t)(2 * jj) * LDQ + h * HD + dcv * 8;
    const unsigned short* vg1 = vg + (size_t)(2 * jj + 1) * LDQ + h * HD + dcv * 8;
    int vtw[8];
#pragma unroll
    for (int e = 0; e < 8; ++e) {
        const int d = dcv * 8 + e;
        const int msk = ((d & 7) ^ (d >> 3)) & 7;
        vtw[e] = d * 32 + (jj ^ (msk << 2));
    }

    // fragment read byte-offsets (tile-invariant)
    int koff[4][2], voff[4][2];
#pragma unroll
    for (int n = 0; n < 4; ++n)
#pragma unroll
        for (int ks = 0; ks < 2; ++ks) {
            const int R = n * 16 + ln;
            koff[n][ks] = R * 128 + (((ks * 4 + lg) ^ (R & 7)) * 16);
            const int d = n * 16 + ln;
            const int msk = ((d & 7) ^ (d >> 3)) & 7;
            voff[n][ks] = (d * 32 + ((ks * 16 + lg * 4) ^ (msk << 2))) * 4;
        }
    const int prow = (w * 16 + ln) * 144;
    const f32x4 z4 = {0.f, 0.f, 0.f, 0.f};

    for (int ph = 0; ph < 2; ++ph) {
        const int st = ph ? p : (nst - 1 - p);
        const int q0 = st * 64;

        // Q fragments in registers (B-operand of swapped QK^T)
        bf16x8 qf[2];
#pragma unroll
        for (int ks = 0; ks < 2; ++ks)
            qf[ks] = *reinterpret_cast<const bf16x8*>(
                qg + (size_t)(q0 + w * 16 + ln) * LDQ + h * HD + ks * 32 + lg * 8);

        f32x4 oa[4];
#pragma unroll
        for (int dn = 0; dn < 4; ++dn) oa[dn] = z4;
        float m_i = -INFINITY, l_i = 0.f;

        // prologue: stage tile 0 into buffer 0
        gload16(kg0, lk0);
        gload16(kg1, lk1);
        {
            uint4 va = *reinterpret_cast<const uint4*>(vg0);
            uint4 vb = *reinterpret_cast<const uint4*>(vg1);
            const unsigned aw[4] = {va.x, va.y, va.z, va.w};
            const unsigned bw[4] = {vb.x, vb.y, vb.z, vb.w};
#pragma unroll
            for (int wv = 0; wv < 4; ++wv) {
                Vt[vtw[wv * 2]]     = __builtin_amdgcn_perm(bw[wv], aw[wv], 0x05040100u);
                Vt[vtw[wv * 2 + 1]] = __builtin_amdgcn_perm(bw[wv], aw[wv], 0x07060302u);
            }
        }
        __syncthreads();

        const int ntk = st + 1;
        for (int kt = 0; kt < ntk; ++kt) {
            const int bsel = kt & 1;
            const int kv0 = kt * 64;
            const char* KsB = (const char*)Ks + bsel * 8192;
            const char* VtB = (const char*)Vt + bsel * 8192;

            uint4 pva, pvb;
            const bool hasNext = (kt + 1 < ntk);
            if (hasNext) {  // issue next-tile staging before compute (T3/T14)
                const size_t adv = (size_t)(kt + 1) * 64 * LDQ;
                gload16(kg0 + adv, lk0 + (bsel ^ 1) * 4096);
                gload16(kg1 + adv, lk1 + (bsel ^ 1) * 4096);
                pva = *reinterpret_cast<const uint4*>(vg0 + adv);
                pvb = *reinterpret_cast<const uint4*>(vg1 + adv);
            }

            // S^T = mfma(K, Q): rows = kv, cols = q (scores pre-scaled by
            // log2e/8 via Q)
            bf16x8 kf[4][2];
#pragma unroll
            for (int n = 0; n < 4; ++n)
#pragma unroll
                for (int ks = 0; ks < 2; ++ks)
                    kf[n][ks] = *reinterpret_cast<const bf16x8*>(KsB + koff[n][ks]);
            f32x4 s[4];
            __builtin_amdgcn_s_setprio(1);
#pragma unroll
            for (int n = 0; n < 4; ++n) {
                f32x4 acc = MFMA_BF16(kf[n][0], qf[0], z4);
                s[n] = MFMA_BF16(kf[n][1], qf[1], acc);
            }
            __builtin_amdgcn_s_setprio(0);

            // causal mask (diagonal tile only)
            if (kv0 + 63 > q0 + w * 16) {
                const int qq = q0 + w * 16 + ln;
#pragma unroll
                for (int n = 0; n < 4; ++n)
#pragma unroll
                    for (int rg = 0; rg < 4; ++rg)
                        if (kv0 + n * 16 + lg * 4 + rg > qq) s[n][rg] = -INFINITY;
            }

            // online softmax, defer-max (T13): skip rescale while growth <= 8
            float mx = fmaxf(fmaxf(s[0][0], s[0][1]), fmaxf(s[0][2], s[0][3]));
#pragma unroll
            for (int n = 1; n < 4; ++n)
                mx = fmaxf(mx, fmaxf(fmaxf(s[n][0], s[n][1]),
                                     fmaxf(s[n][2], s[n][3])));
            mx = fmaxf(mx, __shfl_xor(mx, 16));
            mx = fmaxf(mx, __shfl_xor(mx, 32));
            if (__any(mx > m_i + 8.f)) {
                const float mn = fmaxf(m_i, mx);
                const float sc = exp2f(m_i - mn);
                m_i = mn;
                l_i *= sc;
#pragma unroll
                for (int dn = 0; dn < 4; ++dn) oa[dn] *= sc;
            }
            float ps = 0.f;
#pragma unroll
            for (int n = 0; n < 4; ++n)
#pragma unroll
                for (int rg = 0; rg < 4; ++rg) {
                    const float pv = __builtin_amdgcn_exp2f(s[n][rg] - m_i);
                    s[n][rg] = pv;
                    ps += pv;
                }
            ps += __shfl_xor(ps, 16);
            ps += __shfl_xor(ps, 32);
            l_i += ps;

            // P -> PV B-operand fragments, fully in-register (T12)
            bf16x8 pf0 = pack_swap(s[0], s[1]);
            bf16x8 pf1 = pack_swap(s[2], s[3]);

            // O^T += mfma(V^T, P)
            bf16x8 vf[4][2];
#pragma unroll
            for (int dn = 0; dn < 4; ++dn)
#pragma unroll
                for (int ks = 0; ks < 2; ++ks)
                    vf[dn][ks] = *reinterpret_cast<const bf16x8*>(VtB + voff[dn][ks]);
            __builtin_amdgcn_s_setprio(1);
#pragma unroll
            for (int dn = 0; dn < 4; ++dn) {
                oa[dn] = MFMA_BF16(vf[dn][0], pf0, oa[dn]);
                oa[dn] = MFMA_BF16(vf[dn][1], pf1, oa[dn]);
            }
            __builtin_amdgcn_s_setprio(0);

            if (hasNext) {  // late V transpose-write into the other buffer
                unsigned* VtN = Vt + (bsel ^ 1) * 2048;
                const unsigned aw[4] = {pva.x, pva.y, pva.z, pva.w};
                const unsigned bw[4] = {pvb.x, pvb.y, pvb.z, pvb.w};
#pragma unroll
                for (int wv = 0; wv < 4; ++wv) {
                    VtN[vtw[wv * 2]]     = __builtin_amdgcn_perm(bw[wv], aw[wv], 0x05040100u);
                    VtN[vtw[wv * 2 + 1]] = __builtin_amdgcn_perm(bw[wv], aw[wv], 0x07060302u);
                }
            }
            __syncthreads();  // single barrier per tile (drains vmcnt + lgkm)
        }

        // epilogue: normalize, transpose O^T -> O via Ps, coalesced store
        {
            const float inv = 1.f / l_i;
#pragma unroll
            for (int dn = 0; dn < 4; ++dn) {
                f32x4 o = oa[dn] * inv;
                const unsigned u0 = cvt_pk_bf16(o[0], o[1]);
                const unsigned u1 = cvt_pk_bf16(o[2], o[3]);
                *reinterpret_cast<uint2*>((char*)Ps + prow + dn * 32 + lg * 8) =
                    make_uint2(u0, u1);
            }
            __syncthreads();
#pragma unroll
            for (int it = 0; it < 2; ++it) {
                const int a = it * 256 + t;
                const int r = a >> 3, c = (a & 7) * 8;
                const bf16x8 vv =
                    *reinterpret_cast<const bf16x8*>((const char*)Ps + r * 144 + c * 2);
                *reinterpret_cast<bf16x8*>(ob + (size_t)(q0 + r) * DM + h * HD + c) = vv;
            }
            __syncthreads();  // Ps / LDS safe before next phase
        }
    }
}

extern "C" void kernel_launch(void* const* d_in, const int* in_sizes, int n_in,
                              void* d_out, int out_size, void* d_ws, size_t ws_size,
                              hipStream_t stream) {
    const float* x  = (const float*)d_in[0];
    const float* wq = (const float*)d_in[1];
    const float* wk = (const float*)d_in[2];
    const float* wv = (const float*)d_in[3];
    const float* wo = (const float*)d_in[4];

    const int L = in_sizes[0] / DM;          // 4096
    const size_t NE = (size_t)L * DM;        // 4M
    const size_t W  = (size_t)DM * DM;       // 1M

    unsigned short* xb   = (unsigned short*)d_ws;
    unsigned short* wqb  = xb + NE;          // wq|wk|wv contiguous for fused GEMM
    unsigned short* wob  = wqb + 3 * W;
    unsigned short* qkvb = wob + W;          // [L][3072]
    unsigned short* ab   = qkvb + (size_t)L * LDQ;

    const long long totalConv = (long long)(NE + 4 * W);  // 8M
    convert_bf16<<<dim3((unsigned)(totalConv / 8 / 256)), dim3(256), 0, stream>>>(
        x, wq, wk, wv, wo, xb, (long long)NE);

    // fused q|k|v projection: C[L][3072] = x @ [wq;wk;wv]^T
    gemm_bf16<unsigned short><<<dim3(LDQ / 128, L / 128), dim3(256), 0, stream>>>(
        xb, wqb, qkvb, L, LDQ, DM);

    rope_bf16<<<dim3(L), dim3(512), 0, stream>>>(qkvb);

    // balanced causal attention: pairs (nst-1-p, p), nst = L/64 strips
    attn_mfma<<<dim3(L / 128, NH), dim3(256), 0, stream>>>(qkvb, ab, L / 64);

    gemm_bf16<float><<<dim3(DM / 128, L / 128), dim3(256), 0, stream>>>(
        ab, wob, (float*)d_out, L, DM, DM);
}